// Round 1
// baseline (591.724 us; speedup 1.0000x reference)
//
#include <hip/hip_runtime.h>

typedef _Float16 half_t;
typedef __attribute__((ext_vector_type(8))) _Float16 half8;
typedef __attribute__((ext_vector_type(4))) _Float16 half4;
typedef __attribute__((ext_vector_type(4))) float f32x4;

#define B_ 4
#define N_ 4096
#define D_ 1024
#define R_ (B_ * N_) // 16384

// ---------------------------------------------------------------------------
// async global->LDS, 16B per lane. LDS dest must be wave-uniform base + lane*16.
__device__ __forceinline__ void gload_lds16(const half_t* g, half_t* l) {
    __builtin_amdgcn_global_load_lds(
        (const __attribute__((address_space(1))) unsigned int*)g,
        (__attribute__((address_space(3))) unsigned int*)l, 16, 0, 0);
}

// ---------------------------------------------------------------------------
// C[m,n] = sum_k A[m,k] * Bt[n,k]   (A row-major [M,K], B given transposed [N,K])
// 128x128 tile, BK=32, 256 threads (4 waves, each 64x64 = 4x4 MFMA 16x16x32).
// EPI: 0 = fp32 C, 1 = f16 C, 2 = fp32 C + bias (bias indexed by column)
template <int EPI>
__global__ __launch_bounds__(256) void gemm_bt(
    const half_t* __restrict__ A, const half_t* __restrict__ Bt,
    void* __restrict__ Cv, const float* __restrict__ bias,
    int lda, int ldb, int ldc, int K,
    long sA, long sB, long sC, float scale)
{
    __shared__ __align__(16) half_t As[128 * 32];
    __shared__ __align__(16) half_t Bs[128 * 32];

    const int t = threadIdx.x;
    const int wave = t >> 6;
    const int lane = t & 63;
    const int l15 = lane & 15;
    const int q = lane >> 4;
    const int m0 = blockIdx.y * 128;
    const int n0 = blockIdx.x * 128;
    const long z = blockIdx.z;

    const half_t* Ap = A + z * sA + (long)m0 * lda;
    const half_t* Bp = Bt + z * sB + (long)n0 * ldb;

    // staging: idx in [0,512): row = idx>>2 (for idx<256) / +64, kchunk = (idx&3)*8
    const int r0 = t >> 2;
    const int c0 = (t & 3) * 8;

    f32x4 acc[4][4] = {};

    const int wr = (wave >> 1) * 64;
    const int wc = (wave & 1) * 64;

    for (int k0 = 0; k0 < K; k0 += 32) {
        gload_lds16(Ap + (long)r0 * lda + (k0 + c0), As + t * 8);
        gload_lds16(Ap + (long)(r0 + 64) * lda + (k0 + c0), As + (t + 256) * 8);
        gload_lds16(Bp + (long)r0 * ldb + (k0 + c0), Bs + t * 8);
        gload_lds16(Bp + (long)(r0 + 64) * ldb + (k0 + c0), Bs + (t + 256) * 8);
        __syncthreads();

        half8 af[4], bfr[4];
#pragma unroll
        for (int i = 0; i < 4; i++)
            af[i] = *(const half8*)(As + (wr + i * 16 + l15) * 32 + q * 8);
#pragma unroll
        for (int j = 0; j < 4; j++)
            bfr[j] = *(const half8*)(Bs + (wc + j * 16 + l15) * 32 + q * 8);
#pragma unroll
        for (int i = 0; i < 4; i++)
#pragma unroll
            for (int j = 0; j < 4; j++)
                acc[i][j] = __builtin_amdgcn_mfma_f32_16x16x32_f16(af[i], bfr[j], acc[i][j], 0, 0, 0);
        __syncthreads();
    }

    if (EPI == 1) {
        half_t* C = (half_t*)Cv + z * sC + (long)m0 * ldc + n0;
#pragma unroll
        for (int i = 0; i < 4; i++)
#pragma unroll
            for (int j = 0; j < 4; j++) {
                const int col = wc + j * 16 + l15;
#pragma unroll
                for (int r = 0; r < 4; r++) {
                    const int row = wr + i * 16 + q * 4 + r;
                    C[(long)row * ldc + col] = (half_t)(acc[i][j][r] * scale);
                }
            }
    } else {
        float* C = (float*)Cv + z * sC + (long)m0 * ldc + n0;
#pragma unroll
        for (int i = 0; i < 4; i++)
#pragma unroll
            for (int j = 0; j < 4; j++) {
                const int col = wc + j * 16 + l15;
                const float bv = (EPI == 2) ? bias[n0 + col] : 0.0f;
#pragma unroll
                for (int r = 0; r < 4; r++) {
                    const int row = wr + i * 16 + q * 4 + r;
                    C[(long)row * ldc + col] = acc[i][j][r] * scale + bv;
                }
            }
    }
}

// ---------------------------------------------------------------------------
// fp32 -> f16 elementwise (8 elems/thread)
__global__ __launch_bounds__(256) void convert_f32_f16(
    const float* __restrict__ in, half_t* __restrict__ out)
{
    const long i = ((long)blockIdx.x * 256 + threadIdx.x) * 8;
    const float4 a = *(const float4*)(in + i);
    const float4 b = *(const float4*)(in + i + 4);
    half8 o = {(half_t)a.x, (half_t)a.y, (half_t)a.z, (half_t)a.w,
               (half_t)b.x, (half_t)b.y, (half_t)b.z, (half_t)b.w};
    *(half8*)(out + i) = o;
}

// ---------------------------------------------------------------------------
// 1024x1024 fp32 -> f16 transposed (Wt[j][i] = W[i][j]); block (32,8)
__global__ void transpose_w(const float* __restrict__ W, half_t* __restrict__ Wt)
{
    __shared__ float tile[32][33];
    const int tx = threadIdx.x, ty = threadIdx.y;
    const int bx = blockIdx.x * 32, by = blockIdx.y * 32;
#pragma unroll
    for (int yy = ty; yy < 32; yy += 8)
        tile[yy][tx] = W[(long)(by + yy) * 1024 + bx + tx];
    __syncthreads();
#pragma unroll
    for (int yy = ty; yy < 32; yy += 8)
        Wt[(long)(bx + yy) * 1024 + by + tx] = (half_t)tile[tx][yy];
}

// ---------------------------------------------------------------------------
// row softmax over 1024 features; one block per row. Output scaled by 64 (f16
// subnormal guard; compensated in final epilogue scale).
__global__ __launch_bounds__(256) void softmax_rows(
    const float* __restrict__ L, half_t* __restrict__ Qh)
{
    const int r = blockIdx.x;
    const int t = threadIdx.x;
    const float4 x = ((const float4*)(L + (long)r * 1024))[t];
    float m = fmaxf(fmaxf(x.x, x.y), fmaxf(x.z, x.w));
#pragma unroll
    for (int o = 32; o > 0; o >>= 1) m = fmaxf(m, __shfl_xor(m, o, 64));
    __shared__ float redm[4], reds[4];
    const int wave = t >> 6;
    if ((t & 63) == 0) redm[wave] = m;
    __syncthreads();
    m = fmaxf(fmaxf(redm[0], redm[1]), fmaxf(redm[2], redm[3]));
    const float e0 = __expf(x.x - m), e1 = __expf(x.y - m),
                e2 = __expf(x.z - m), e3 = __expf(x.w - m);
    float s = e0 + e1 + e2 + e3;
#pragma unroll
    for (int o = 32; o > 0; o >>= 1) s += __shfl_xor(s, o, 64);
    if ((t & 63) == 0) reds[wave] = s;
    __syncthreads();
    s = reds[0] + reds[1] + reds[2] + reds[3];
    const float rs = 64.0f / s;
    half4 o4 = {(half_t)(e0 * rs), (half_t)(e1 * rs),
                (half_t)(e2 * rs), (half_t)(e3 * rs)};
    ((half4*)(Qh + (long)r * 1024))[t] = o4;
}

// ---------------------------------------------------------------------------
// column softmax stats over N per (b,d): partial online max/sum per 256-row chunk
__global__ __launch_bounds__(256) void colstat1(
    const float* __restrict__ L, float* __restrict__ pm, float* __restrict__ ps)
{
    const int t = threadIdx.x;
    const int d = blockIdx.x * 256 + t;
    const int nc = blockIdx.y, b = blockIdx.z;
    const float* p = L + ((long)(b * N_ + nc * 256)) * 1024 + d;
    float m = -1e30f, s = 0.0f;
    for (int i = 0; i < 256; i++) {
        const float x = p[(long)i * 1024];
        const float nm = fmaxf(m, x);
        s = s * __expf(m - nm) + __expf(x - nm);
        m = nm;
    }
    const int o = (b * 16 + nc) * 1024 + d;
    pm[o] = m;
    ps[o] = s;
}

__global__ __launch_bounds__(256) void colstat2(
    const float* __restrict__ pm, const float* __restrict__ ps,
    float* __restrict__ cmax, float* __restrict__ crcp)
{
    const int c = blockIdx.x * 256 + threadIdx.x; // [0, 4096)
    const int b = c >> 10, d = c & 1023;
    float m = -1e30f;
#pragma unroll
    for (int j = 0; j < 16; j++) m = fmaxf(m, pm[(b * 16 + j) * 1024 + d]);
    float s = 0.0f;
#pragma unroll
    for (int j = 0; j < 16; j++)
        s += ps[(b * 16 + j) * 1024 + d] * __expf(pm[(b * 16 + j) * 1024 + d] - m);
    cmax[c] = m;
    crcp[c] = 1.0f / s;
}

// ---------------------------------------------------------------------------
// [B,N,D] fp32 -> [B,D,N] f16, optionally applying column softmax (exp/Z * 64)
template <bool SM>
__global__ __launch_bounds__(256) void transpose_nd(
    const float* __restrict__ L, half_t* __restrict__ Out,
    const float* __restrict__ cmax, const float* __restrict__ crcp)
{
    __shared__ half_t tile[64][66]; // 66: odd word stride -> conflict-free
    const int t = threadIdx.x;
    const int n0 = blockIdx.x * 64, d0 = blockIdx.y * 64;
    const int b = blockIdx.z;
    const float* src = L + ((long)(b * N_ + n0)) * 1024 + d0;
#pragma unroll
    for (int i = 0; i < 16; i++) {
        const int idx = i * 256 + t;
        const int nl = idx >> 6, dl = idx & 63;
        float x = src[(long)nl * 1024 + dl];
        if (SM)
            x = __expf(x - cmax[b * 1024 + d0 + dl]) * (64.0f * crcp[b * 1024 + d0 + dl]);
        tile[dl][nl] = (half_t)x;
    }
    __syncthreads();
    half_t* dst = Out + ((long)(b * 1024 + d0)) * (long)N_ + n0;
#pragma unroll
    for (int i = 0; i < 16; i++) {
        const int idx = i * 256 + t;
        const int dl = idx >> 6, nl = idx & 63;
        dst[(long)dl * N_ + nl] = tile[dl][nl];
    }
}

// ---------------------------------------------------------------------------
extern "C" void kernel_launch(void* const* d_in, const int* in_sizes, int n_in,
                              void* d_out, int out_size, void* d_ws, size_t ws_size,
                              hipStream_t stream)
{
    const float* x  = (const float*)d_in[0];
    const float* Wq = (const float*)d_in[1];
    const float* Wk = (const float*)d_in[2];
    const float* Wv = (const float*)d_in[3];
    const float* Wo = (const float*)d_in[4];
    const float* bo = (const float*)d_in[5];
    float* out = (float*)d_out;

    char* w = (char*)d_ws;
    half_t* Xh  = (half_t*)w; w += (size_t)R_ * D_ * 2;       // 32 MiB
    float*  L   = (float*)w;  w += (size_t)R_ * D_ * 4;       // 64 MiB (reused Q/K/V)
    half_t* Qh  = (half_t*)w; w += (size_t)R_ * D_ * 2;       // 32 MiB (q * 64)
    half_t* Kt  = (half_t*)w; w += (size_t)R_ * D_ * 2;       // 32 MiB [B,D,N] (k * 64)
    half_t* Vt  = (half_t*)w; w += (size_t)R_ * D_ * 2;       // 32 MiB [B,D,N]
    half_t* Wt  = (half_t*)w; w += (size_t)D_ * D_ * 2;       // 2 MiB (reused)
    half_t* ctx = (half_t*)w; w += (size_t)B_ * D_ * D_ * 2;  // 8 MiB (64 * K^T V)
    half_t* Mt  = (half_t*)w; w += (size_t)B_ * D_ * D_ * 2;  // 8 MiB (64 * (ctx Wo)^T)
    float*  pm  = (float*)w;  w += (size_t)B_ * 16 * D_ * 4;
    float*  ps  = (float*)w;  w += (size_t)B_ * 16 * D_ * 4;
    float*  cmx = (float*)w;  w += (size_t)B_ * D_ * 4;
    float*  crp = (float*)w;  w += (size_t)B_ * D_ * 4;
    (void)ws_size; (void)in_sizes; (void)n_in; (void)out_size;

    const dim3 blk(256);
    const dim3 twb(32, 8), twg(32, 32);

    convert_f32_f16<<<R_ * D_ / (256 * 8), blk, 0, stream>>>(x, Xh);

    // ---- Q path
    transpose_w<<<twg, twb, 0, stream>>>(Wq, Wt);
    gemm_bt<0><<<dim3(8, 128, 1), blk, 0, stream>>>(Xh, Wt, L, nullptr,
        1024, 1024, 1024, 1024, 0, 0, 0, 1.0f);
    softmax_rows<<<R_, blk, 0, stream>>>(L, Qh);

    // ---- K path (column softmax over sequence, then transpose to [B,D,N])
    transpose_w<<<twg, twb, 0, stream>>>(Wk, Wt);
    gemm_bt<0><<<dim3(8, 128, 1), blk, 0, stream>>>(Xh, Wt, L, nullptr,
        1024, 1024, 1024, 1024, 0, 0, 0, 1.0f);
    colstat1<<<dim3(4, 16, B_), blk, 0, stream>>>(L, pm, ps);
    colstat2<<<16, blk, 0, stream>>>(pm, ps, cmx, crp);
    transpose_nd<true><<<dim3(64, 16, B_), blk, 0, stream>>>(L, Kt, cmx, crp);

    // ---- V path (transpose to [B,D,N])
    transpose_w<<<twg, twb, 0, stream>>>(Wv, Wt);
    gemm_bt<0><<<dim3(8, 128, 1), blk, 0, stream>>>(Xh, Wt, L, nullptr,
        1024, 1024, 1024, 1024, 0, 0, 0, 1.0f);
    transpose_nd<false><<<dim3(64, 16, B_), blk, 0, stream>>>(L, Vt, nullptr, nullptr);

    // ---- ctx[b][d][e] = sum_n (64 k[n,d]) v[n,e]   (A=Kt, Bt=Vt, K=4096)
    gemm_bt<1><<<dim3(8, 8, B_), blk, 0, stream>>>(Kt, Vt, ctx, nullptr,
        N_, N_, 1024, N_,
        (long)D_ * N_, (long)D_ * N_, (long)D_ * D_, 1.0f);

    // ---- Mt[b][e][d] = sum_f Wo[f][e] * ctx[b][d][f]   (A=Wo^T, Bt=ctx)
    transpose_w<<<twg, twb, 0, stream>>>(Wo, Wt);
    gemm_bt<1><<<dim3(8, 8, B_), blk, 0, stream>>>(Wt, ctx, Mt, nullptr,
        1024, 1024, 1024, 1024,
        0, (long)D_ * D_, (long)D_ * D_, 1.0f);

    // ---- out[b][n][e] = (sum_d 64 q[n,d] * Mt[b][e][d]) * 2^-25 + bo[e]
    // 2^-25 = (1/8 head scale) * (1/1024 D_OUT) * (1/64 q) * (1/64 k), all exact
    gemm_bt<2><<<dim3(8, 32, B_), blk, 0, stream>>>(Qh, Mt, out, bo,
        1024, 1024, 1024, 1024,
        (long)N_ * D_, (long)D_ * D_, (long)N_ * D_,
        1.0f / 33554432.0f);
}